// Round 5
// baseline (874.237 us; speedup 1.0000x reference)
//
#include <hip/hip_runtime.h>

// Qwen3 attention block, MI355X gfx950.
// Round 10: L2-LOCALITY + DEEPER PREFETCH. Round-9 counters: QKV gemm 278us,
// FETCH_SIZE 668MB at 2.58TB/s fill rate == the whole duration -> L2-fill
// bound. Old swizzle gave each XCD a by-band (all 48 B-panels stream through
// 4MB L2 with no reuse -> ~650MB fills). This round:
//  - bx-major XCD ordering, by-fastest within bx-group: the 16 blocks
//    sharing a B-panel run in lock-step -> B fetched ~once per XCD.
//  - 3-deep reg prefetch (2 named reg sets, load t+2 before compute t);
//    fp32->bf16 conversion at load time (staging regs bf16).
//  - flash_attn / norm_rope / convert_x unchanged (validated round 8).
// ws (24 MiB + 4 KiB): [0,4K) control {flag, qwc[128], kwc[128]}
//   [4K,+4M) kq bf16 | [+4M,+8M) vb bf16 | [+8M,+24M) xb bf16 then attnbuf
// d_out (fp32): out [0,8388608) | k [8388608,10485760) | v [10485760,12582912)
//   (bf16 q scratch borrows out's first 16 MiB; overwritten by final gemm)

typedef __bf16 bf16;
typedef __bf16 bf16x8 __attribute__((ext_vector_type(8)));
typedef float  f32x4  __attribute__((ext_vector_type(4)));

#define MFMA16(a, b, c) __builtin_amdgcn_mfma_f32_16x16x32_bf16((a), (b), (c), 0, 0, 0)

// ---------------------------------------------------------------- dtype probe
__global__ __launch_bounds__(256) void detect_convert(
    const unsigned short* __restrict__ probe,   // Wq bits
    const void* __restrict__ qw_raw, const void* __restrict__ kw_raw,
    int* __restrict__ flag, bf16* __restrict__ qwc, bf16* __restrict__ kwc) {
    __shared__ int cnt;
    if (threadIdx.x == 0) cnt = 0;
    __syncthreads();
    int local = 0;
    for (int i = 0; i < 4; ++i) {
        const unsigned short w = probe[(threadIdx.x * 4 + i) * 2];
        const int e = (w >> 7) & 0xFF;
        if (e >= 90 && e <= 140) ++local;
    }
    atomicAdd(&cnt, local);
    __syncthreads();
    const bool isbf16 = cnt >= 700;
    if (threadIdx.x == 0) *flag = isbf16 ? 1 : 0;
    const int t = threadIdx.x;
    if (t < 128)
        qwc[t] = isbf16 ? ((const bf16*)qw_raw)[t] : (bf16)((const float*)qw_raw)[t];
    else
        kwc[t - 128] = isbf16 ? ((const bf16*)kw_raw)[t - 128] : (bf16)((const float*)kw_raw)[t - 128];
}

// ---------------------------------------------------------------- x -> bf16
__global__ __launch_bounds__(256) void convert_x(const void* __restrict__ xv,
                                                 bf16* __restrict__ xb,
                                                 const int* __restrict__ flag) {
    const size_t i8 = ((size_t)blockIdx.x * 256 + threadIdx.x) * 8;
    if (*flag) {
        *(bf16x8*)&xb[i8] = *(const bf16x8*)&((const bf16*)xv)[i8];
    } else {
        const f32x4 a = *(const f32x4*)&((const float*)xv)[i8];
        const f32x4 b = *(const f32x4*)&((const float*)xv)[i8 + 4];
        bf16x8 o;
#pragma unroll
        for (int e = 0; e < 4; ++e) { o[e] = (bf16)a[e]; o[e + 4] = (bf16)b[e]; }
        *(bf16x8*)&xb[i8] = o;
    }
}

// ---------------------------------------------------------------- MFMA GEMM
// A bf16 [M][K] row-major. B (fp32 or bf16 via flag) [K][N] row-major.
// Up to three B/C sets split along bx. bx-major XCD ordering (by-fastest):
// blocks sharing a B-panel run lock-step so the panel's k-slices stay
// L2-hot. 3-deep pipeline: regs for t+2 issued before compute of t.
#define GBM 128
#define GBN 128
#define GBK 64
#define GLD 72

__global__ __launch_bounds__(256) void gemm_nt(
    const bf16* __restrict__ A,
    const void* __restrict__ B1v, const void* __restrict__ B2v, const void* __restrict__ B3v,
    bf16* __restrict__ Cb1, float* __restrict__ Cf1,
    bf16* __restrict__ Cb2, float* __restrict__ Cf2,
    bf16* __restrict__ Cb3, float* __restrict__ Cf3,
    const int* __restrict__ flag, int K,
    int ldb1, int ldb2, int ldb3, int ldc1, int ldc2, int ldc3,
    int ns1, int ns2) {
    __shared__ __align__(16) bf16 As[2][GBM * GLD];
    __shared__ __align__(16) bf16 Bs[2][GBN * GLD];

    // bx-major XCD ordering: XCD x owns bx in [x*nbxp, (x+1)*nbxp), by-fastest.
    // (gridDim.x % 8 == 0 for all launches)
    {
    }
    const int nbxp = (int)gridDim.x >> 3;
    int id = blockIdx.y * gridDim.x + blockIdx.x;
    const int xcd = id & 7;
    const int j = id >> 3;
    const int bx = xcd * nbxp + j / (int)gridDim.y;
    const int by = j % (int)gridDim.y;

    const void* Bv;
    bf16* Cb;
    float* Cf;
    int n0, ldb, ldc;
    if (bx < ns1) {
        Bv = B1v; Cb = Cb1; Cf = Cf1; n0 = bx * GBN; ldb = ldb1; ldc = ldc1;
    } else if (bx < ns1 + ns2) {
        Bv = B2v; Cb = Cb2; Cf = Cf2; n0 = (bx - ns1) * GBN; ldb = ldb2; ldc = ldc2;
    } else {
        Bv = B3v; Cb = Cb3; Cf = Cf3; n0 = (bx - ns1 - ns2) * GBN; ldb = ldb3; ldc = ldc3;
    }
    const int m0 = by * GBM;

    const bool bBf16 = (*flag) != 0;
    const bf16*  Bb = (const bf16*)Bv;
    const float* Bf = (const float*)Bv;

    const int tid  = threadIdx.x;
    const int wave = tid >> 6;
    const int lane = tid & 63;
    const int l15  = lane & 15;
    const int quad = lane >> 4;
    const int wm = (wave >> 1) * 64;
    const int wn = (wave & 1) * 64;

    // per-thread staging coords (constant across tiles)
    const int ar[4] = { (0 * 256 + tid) >> 3, (1 * 256 + tid) >> 3,
                        (2 * 256 + tid) >> 3, (3 * 256 + tid) >> 3 };
    const int ak = tid & 7;

    f32x4 acc[4][4];
#pragma unroll
    for (int i = 0; i < 4; ++i)
#pragma unroll
        for (int j2 = 0; j2 < 4; ++j2) acc[i][j2] = {0.f, 0.f, 0.f, 0.f};

    // two named staging sets (rule #20: no runtime-indexed reg arrays)
    bf16x8 aR0[4], aR1[4];
    bf16   bR0[4][8], bR1[4][8];

#define LOAD_TILE(k0, aR, bR)                                                  \
    {                                                                          \
        _Pragma("unroll")                                                      \
        for (int p = 0; p < 4; ++p)                                            \
            aR[p] = *(const bf16x8*)&A[(size_t)(m0 + ar[p]) * K + (k0) + ak * 8]; \
        if (bBf16) {                                                           \
            _Pragma("unroll")                                                  \
            for (int p = 0; p < 4; ++p) {                                      \
                const int w16 = wave * 4 + p;                                  \
                const int n = (w16 & 1) * 64 + lane, kc = w16 >> 1;            \
                _Pragma("unroll")                                              \
                for (int e = 0; e < 8; ++e)                                    \
                    bR[p][e] = Bb[(size_t)((k0) + kc * 8 + e) * ldb + n0 + n]; \
            }                                                                  \
        } else {                                                               \
            _Pragma("unroll")                                                  \
            for (int p = 0; p < 4; ++p) {                                      \
                const int w16 = wave * 4 + p;                                  \
                const int n = (w16 & 1) * 64 + lane, kc = w16 >> 1;            \
                _Pragma("unroll")                                              \
                for (int e = 0; e < 8; ++e)                                    \
                    bR[p][e] = (bf16)Bf[(size_t)((k0) + kc * 8 + e) * ldb + n0 + n]; \
            }                                                                  \
        }                                                                      \
    }

#define WRITE_TILE(buf, aR, bR)                                                \
    {                                                                          \
        _Pragma("unroll")                                                      \
        for (int p = 0; p < 4; ++p)                                            \
            *(bf16x8*)&As[buf][ar[p] * GLD + ak * 8] = aR[p];                  \
        _Pragma("unroll")                                                      \
        for (int p = 0; p < 4; ++p) {                                          \
            const int w16 = wave * 4 + p;                                      \
            const int n = (w16 & 1) * 64 + lane, kc = w16 >> 1;                \
            bf16x8 bv;                                                         \
            _Pragma("unroll")                                                  \
            for (int e = 0; e < 8; ++e) bv[e] = bR[p][e];                      \
            *(bf16x8*)&Bs[buf][n * GLD + kc * 8] = bv;                         \
        }                                                                      \
    }

#define COMPUTE_TILE(buf)                                                      \
    {                                                                          \
        _Pragma("unroll")                                                      \
        for (int kk = 0; kk < GBK; kk += 32) {                                 \
            bf16x8 af[4], bfr[4];                                              \
            _Pragma("unroll")                                                  \
            for (int i = 0; i < 4; ++i)                                        \
                af[i] = *(const bf16x8*)&As[buf][(wm + i * 16 + l15) * GLD + kk + quad * 8]; \
            _Pragma("unroll")                                                  \
            for (int j3 = 0; j3 < 4; ++j3)                                     \
                bfr[j3] = *(const bf16x8*)&Bs[buf][(wn + j3 * 16 + l15) * GLD + kk + quad * 8]; \
            _Pragma("unroll")                                                  \
            for (int i = 0; i < 4; ++i)                                        \
                _Pragma("unroll")                                              \
                for (int j3 = 0; j3 < 4; ++j3)                                 \
                    acc[i][j3] = MFMA16(af[i], bfr[j3], acc[i][j3]);           \
        }                                                                      \
    }

    const int nt = K >> 6;   // GBK = 64
    // prologue: T0 -> lds0; T1 -> set1
    LOAD_TILE(0, aR0, bR0);
    WRITE_TILE(0, aR0, bR0);
    __syncthreads();
    if (nt > 1) LOAD_TILE(1 << 6, aR1, bR1);
    // steady loop, unrolled by 2 (nt assumed >= 2; tail handles odd nt)
    for (int t = 0; t + 2 <= nt; t += 2) {
        // even half: compute lds0 (tile t); set1 holds t+1
        if (t + 2 < nt) LOAD_TILE((t + 2) << 6, aR0, bR0);
        COMPUTE_TILE(0);
        WRITE_TILE(1, aR1, bR1);
        __syncthreads();
        // odd half: compute lds1 (tile t+1); set0 holds t+2
        if (t + 3 < nt) LOAD_TILE((t + 3) << 6, aR1, bR1);
        COMPUTE_TILE(1);
        if (t + 2 < nt) {
            WRITE_TILE(0, aR0, bR0);
            __syncthreads();
        }
    }
    if (nt & 1) COMPUTE_TILE(0);
#undef LOAD_TILE
#undef WRITE_TILE
#undef COMPUTE_TILE

#pragma unroll
    for (int i = 0; i < 4; ++i)
#pragma unroll
        for (int j2 = 0; j2 < 4; ++j2)
#pragma unroll
            for (int r = 0; r < 4; ++r) {
                const int row = m0 + wm + i * 16 + quad * 4 + r;
                const int col = n0 + wn + j2 * 16 + l15;
                const float v = acc[i][j2][r];
                if (Cb) Cb[(size_t)row * ldc + col] = (bf16)v;
                if (Cf) Cf[(size_t)row * ldc + col] = v;
            }
}

// ---------------------------------------------------------------- norm + rope
__global__ __launch_bounds__(256) void norm_rope(const bf16* __restrict__ src,
                                                 bf16* __restrict__ dst_bf,
                                                 float* __restrict__ dst_f32,
                                                 const bf16* __restrict__ w,
                                                 const int* __restrict__ positions,
                                                 int H) {
    const int wid  = blockIdx.x * 4 + (threadIdx.x >> 6);
    const int lane = threadIdx.x & 63;
    const int token = wid / H, head = wid % H;
    const bf16* s = src + ((size_t)token * H + head) * 128;
    const float f0 = (float)s[lane], f1 = (float)s[lane + 64];
    float ss = f0 * f0 + f1 * f1;
    for (int off = 32; off >= 1; off >>= 1) ss += __shfl_xor(ss, off);
    const float inv_rms = rsqrtf(ss * (1.0f / 128.0f) + 1e-6f);
    const float n0 = f0 * inv_rms * (float)w[lane];
    const float n1 = f1 * inv_rms * (float)w[lane + 64];
    const float pos = (float)positions[token];
    const float inv_ts = expf((float)lane * (-13.815510557964274f / 64.0f));
    const float ang = pos * inv_ts;
    const float sn = sinf(ang), cs = cosf(ang);
    const float o0 = n0 * cs - n1 * sn;
    const float o1 = n1 * cs + n0 * sn;
    const size_t base = ((size_t)token * H + head) * 128;
    if (dst_bf)  { dst_bf[base + lane] = (bf16)o0;  dst_bf[base + lane + 64] = (bf16)o1; }
    if (dst_f32) { dst_f32[base + lane] = o0;       dst_f32[base + lane + 64] = o1; }
}

// ---------------------------------------------------------------- MFMA flash attention
// 1024 blocks; work id chunked so each XCD handles 4 consecutive heads
// (one KV head, ~1MB, resident in its private L2). Block = 4 waves; wave w
// owns q rows [qt*64 + w*16, +16) of head h. KV tiles of 32 keys in LDS.
__global__ __launch_bounds__(256) void flash_attn(const bf16* __restrict__ Q,
                                                  const bf16* __restrict__ Kg,
                                                  const bf16* __restrict__ Vg,
                                                  bf16* __restrict__ Og) {
    __shared__ __align__(16) bf16 Ks[32 * 128];     // 8 KiB, swizzled
    __shared__ __align__(16) bf16 Vt[128 * 40];     // 10 KiB, V^T padded
    __shared__ __align__(16) bf16 Ps[4][16 * 40];   // 5 KiB, per-wave P

    int id = blockIdx.y * 32 + blockIdx.x;
    id = (id & 7) * 128 + (id >> 3);        // XCD-chunked
    const int h  = id >> 5;                 // head-major within chunk
    const int qt = 31 - (id & 31);          // heavy (long-loop) tiles first
    const int kvh  = h >> 2;
    const int tid  = threadIdx.x;
    const int wave = tid >> 6;
    const int lane = tid & 63;
    const int l15  = lane & 15;
    const int quad = lane >> 4;
    const int q0   = qt * 64;
    const int qw0  = q0 + wave * 16;
    const int myq  = qw0 + l15;
    const float scale = 0.08838834764831845f;  // 1/sqrt(128)

    bf16x8 qf[4];
    {
        const bf16* qrow = Q + ((size_t)myq * 32 + h) * 128;
#pragma unroll
        for (int kc = 0; kc < 4; ++kc)
            qf[kc] = *(const bf16x8*)&qrow[kc * 32 + quad * 8];
    }

    f32x4 oacc[8];
#pragma unroll
    for (int i = 0; i < 8; ++i) oacc[i] = {0.f, 0.f, 0.f, 0.f};
    float m_run = -1e30f, l_run = 0.f;

    const int ksr  = tid & 31;
    const int kscb = tid >> 5;
    const int vr0  = (tid & 15) * 2;
    const int vcb  = tid >> 4;

    char* kbytes = (char*)Ks;
    char* vbytes = (char*)Vt;
    char* pbytes = (char*)&Ps[wave][0];

    const int ntiles = (q0 + 64) >> 5;
    for (int kt = 0; kt < ntiles; ++kt) {
        const int kb = kt * 32;
        {
            const bf16* src = Kg + ((size_t)(kb + ksr) * 8 + kvh) * 128;
            const bf16x8 v0 = *(const bf16x8*)&src[kscb * 8];
            const bf16x8 v1 = *(const bf16x8*)&src[(kscb + 8) * 8];
            const int b0 = (ksr * 256 + kscb * 16) ^ ((ksr & 7) << 4);
            const int b1 = (ksr * 256 + (kscb + 8) * 16) ^ ((ksr & 7) << 4);
            *(bf16x8*)(kbytes + b0) = v0;
            *(bf16x8*)(kbytes + b1) = v1;
        }
        {
            const bf16* s0 = Vg + ((size_t)(kb + vr0) * 8 + kvh) * 128 + vcb * 8;
            const bf16x8 a = *(const bf16x8*)s0;
            const bf16x8 b = *(const bf16x8*)(s0 + 1024);
#pragma unroll
            for (int e = 0; e < 8; ++e) {
                union { bf16 hh[2]; unsigned int u; } pk;
                pk.hh[0] = a[e]; pk.hh[1] = b[e];
                *(unsigned int*)(vbytes + (vcb * 8 + e) * 80 + vr0 * 2) = pk.u;
            }
        }
        __syncthreads();

        f32x4 sacc[2];
        sacc[0] = {0.f, 0.f, 0.f, 0.f};
        sacc[1] = {0.f, 0.f, 0.f, 0.f};
#pragma unroll
        for (int st = 0; st < 2; ++st) {
            const int row = st * 16 + l15;
#pragma unroll
            for (int kc = 0; kc < 4; ++kc) {
                const int bofs = (row * 256 + kc * 64 + quad * 16) ^ ((row & 7) << 4);
                const bf16x8 kf = *(const bf16x8*)(kbytes + bofs);
                sacc[st] = MFMA16(kf, qf[kc], sacc[st]);
            }
        }

        float sv[8];
        float pm = -1e30f;
#pragma unroll
        for (int st = 0; st < 2; ++st)
#pragma unroll
            for (int r = 0; r < 4; ++r) {
                const int key = kb + st * 16 + quad * 4 + r;
                float s = sacc[st][r] * scale;
                if (key > myq) s = -1e30f;
                sv[st * 4 + r] = s;
                pm = fmaxf(pm, s);
            }
        pm = fmaxf(pm, __shfl_xor(pm, 16));
        pm = fmaxf(pm, __shfl_xor(pm, 32));
        const float m_new = fmaxf(m_run, pm);
        const float corr = __expf(m_run - m_new);
        float ps = 0.f;
        bf16 pb[8];
#pragma unroll
        for (int i = 0; i < 8; ++i) {
            const float p = __expf(sv[i] - m_new);
            ps += p;
            pb[i] = (bf16)p;
        }
        ps += __shfl_xor(ps, 16);
        ps += __shfl_xor(ps, 32);
        l_run = l_run * corr + ps;
        m_run = m_new;

#pragma unroll
        for (int st = 0; st < 2; ++st)
#pragma unroll
            for (int r = 0; r < 4; ++r)
                *(bf16*)(pbytes + l15 * 80 + (st * 16 + quad * 4 + r) * 2) = pb[st * 4 + r];

        float corrq[4];
#pragma unroll
        for (int r = 0; r < 4; ++r) corrq[r] = __shfl(corr, quad * 4 + r);
#pragma unroll
        for (int nt = 0; nt < 8; ++nt)
#pragma unroll
            for (int r = 0; r < 4; ++r) oacc[nt][r] *= corrq[r];

        const bf16x8 pf = *(const bf16x8*)(pbytes + l15 * 80 + quad * 16);
#pragma unroll
        for (int nt = 0; nt < 8; ++nt) {
            const bf16x8 vf = *(const bf16x8*)(vbytes + (nt * 16 + l15) * 80 + quad * 16);
            oacc[nt] = MFMA16(pf, vf, oacc[nt]);
        }
        __syncthreads();
    }

    const float rinv = 1.0f / l_run;
    float linv[4];
#pragma unroll
    for (int r = 0; r < 4; ++r) linv[r] = __shfl(rinv, quad * 4 + r);
#pragma unroll
    for (int nt = 0; nt < 8; ++nt)
#pragma unroll
        for (int r = 0; r < 4; ++r) {
            const int row = qw0 + quad * 4 + r;
            Og[((size_t)row * 32 + h) * 128 + nt * 16 + l15] = (bf16)(oacc[nt][r] * linv[r]);
        }
}

// ---------------------------------------------------------------- launch
extern "C" void kernel_launch(void* const* d_in, const int* in_sizes, int n_in,
                              void* d_out, int out_size, void* d_ws, size_t ws_size,
                              hipStream_t stream) {
    const void* x  = d_in[0];   // [2048][4096]  fp32 or bf16 (auto-detected)
    const void* Wq = d_in[1];   // [4096][4096]
    const void* Wk = d_in[2];   // [4096][1024]
    const void* Wv = d_in[3];   // [4096][1024]
    const void* Wo = d_in[4];   // [4096][4096]
    const void* qw = d_in[5];   // [128]
    const void* kw = d_in[6];   // [128]
    const int* positions = (const int*)d_in[8];

    char* ws = (char*)d_ws;
    int*  flag    = (int*)ws;
    bf16* qwc     = (bf16*)(ws + 64);
    bf16* kwc     = (bf16*)(ws + 64 + 256);
    bf16* kq      = (bf16*)(ws + 4096);                 // [2048][8][128] bf16
    bf16* vb      = (bf16*)(ws + 4096 + 4194304);       // [2048][8][128] bf16
    bf16* xb      = (bf16*)(ws + 4096 + 8388608);       // [2048][4096] bf16 (pre-flash)
    bf16* attnbuf = (bf16*)(ws + 4096 + 8388608);       // [2048][32][128] bf16 (post-flash)

    float* outf = (float*)d_out;           // [2048][4096] fp32
    float* Kof  = outf + 8388608;          // [2048][8][128] fp32
    float* Vof  = outf + 10485760;         // [2048][8][128] fp32
    bf16*  qb   = (bf16*)d_out;            // bf16 q scratch in out's first 16 MiB

    detect_convert<<<1, 256, 0, stream>>>((const unsigned short*)Wq, qw, kw, flag, qwc, kwc);
    convert_x<<<4096, 256, 0, stream>>>(x, xb, flag);

    // All three projections in ONE launch: bx [0,32) Wq -> qb, [32,40) Wk -> kq,
    // [40,48) Wv -> vb + Vof. 768 blocks.
    gemm_nt<<<dim3(48, 16), 256, 0, stream>>>(
        xb, Wq, Wk, Wv,
        qb, nullptr, kq, nullptr, vb, Vof,
        flag, 4096,
        4096, 1024, 1024, 4096, 1024, 1024,
        32, 8);

    // Norm+RoPE. q in-place bf16; k in-place bf16 (attn input) + fp32 (output 1).
    norm_rope<<<16384, 256, 0, stream>>>(qb, qb, nullptr, qwc, positions, 32);
    norm_rope<<<4096, 256, 0, stream>>>(kq, kq, Kof, kwc, positions, 8);

    // Flash attention (MFMA) -> attnbuf bf16 [2048][32][128] (overwrites xb).
    flash_attn<<<dim3(32, 32), 256, 0, stream>>>(qb, kq, vb, attnbuf);

    // Output projection -> fp32 out (overwrites qb scratch after last use).
    gemm_nt<<<dim3(32, 16), 256, 0, stream>>>(
        attnbuf, Wo, Wo, Wo,
        nullptr, outf, nullptr, nullptr, nullptr, nullptr,
        flag, 4096,
        4096, 4096, 4096, 4096, 4096, 4096,
        32, 0);
}

// Round 6
// 712.272 us; speedup vs baseline: 1.2274x; 1.2274x over previous
//
#include <hip/hip_runtime.h>

// Qwen3 attention block, MI355X gfx950.
// Round 11: ISOLATE THE 2x2. Round-10 changed mapping AND pipeline together:
// FETCH 668->246MB (mapping WORKED) but dur 278->367us, VGPR 112->144,
// occupancy 17->11% (3-deep/two-reg-set pipeline REGRESSED -- fill rate fell
// to 0.67TB/s = stalls, not bandwidth). This round: keep bx-major XCD
// mapping, revert to round-9 single-set 2-phase pipeline (one LOAD/WRITE
// reg set, one barrier per K-step). B converted fp32->bf16 at load time
// (bf16 staging regs). flash_attn / norm_rope / convert_x unchanged.
// ws (24 MiB + 4 KiB): [0,4K) control {flag, qwc[128], kwc[128]}
//   [4K,+4M) kq bf16 | [+4M,+8M) vb bf16 | [+8M,+24M) xb bf16 then attnbuf
// d_out (fp32): out [0,8388608) | k [8388608,10485760) | v [10485760,12582912)
//   (bf16 q scratch borrows out's first 16 MiB; overwritten by final gemm)

typedef __bf16 bf16;
typedef __bf16 bf16x8 __attribute__((ext_vector_type(8)));
typedef float  f32x4  __attribute__((ext_vector_type(4)));

#define MFMA16(a, b, c) __builtin_amdgcn_mfma_f32_16x16x32_bf16((a), (b), (c), 0, 0, 0)

// ---------------------------------------------------------------- dtype probe
__global__ __launch_bounds__(256) void detect_convert(
    const unsigned short* __restrict__ probe,   // Wq bits
    const void* __restrict__ qw_raw, const void* __restrict__ kw_raw,
    int* __restrict__ flag, bf16* __restrict__ qwc, bf16* __restrict__ kwc) {
    __shared__ int cnt;
    if (threadIdx.x == 0) cnt = 0;
    __syncthreads();
    int local = 0;
    for (int i = 0; i < 4; ++i) {
        const unsigned short w = probe[(threadIdx.x * 4 + i) * 2];
        const int e = (w >> 7) & 0xFF;
        if (e >= 90 && e <= 140) ++local;
    }
    atomicAdd(&cnt, local);
    __syncthreads();
    const bool isbf16 = cnt >= 700;
    if (threadIdx.x == 0) *flag = isbf16 ? 1 : 0;
    const int t = threadIdx.x;
    if (t < 128)
        qwc[t] = isbf16 ? ((const bf16*)qw_raw)[t] : (bf16)((const float*)qw_raw)[t];
    else
        kwc[t - 128] = isbf16 ? ((const bf16*)kw_raw)[t - 128] : (bf16)((const float*)kw_raw)[t - 128];
}

// ---------------------------------------------------------------- x -> bf16
__global__ __launch_bounds__(256) void convert_x(const void* __restrict__ xv,
                                                 bf16* __restrict__ xb,
                                                 const int* __restrict__ flag) {
    const size_t i8 = ((size_t)blockIdx.x * 256 + threadIdx.x) * 8;
    if (*flag) {
        *(bf16x8*)&xb[i8] = *(const bf16x8*)&((const bf16*)xv)[i8];
    } else {
        const f32x4 a = *(const f32x4*)&((const float*)xv)[i8];
        const f32x4 b = *(const f32x4*)&((const float*)xv)[i8 + 4];
        bf16x8 o;
#pragma unroll
        for (int e = 0; e < 4; ++e) { o[e] = (bf16)a[e]; o[e + 4] = (bf16)b[e]; }
        *(bf16x8*)&xb[i8] = o;
    }
}

// ---------------------------------------------------------------- MFMA GEMM
// A bf16 [M][K] row-major. B (fp32 or bf16 via flag) [K][N] row-major.
// Up to three B/C sets split along bx. bx-major XCD ordering (by-fastest):
// blocks sharing a B-panel run lock-step so the panel's k-slices stay
// L2-hot. Round-9 2-phase pipeline: one staging reg set, loads for t+1
// issued before compute of t, ds_write after, ONE barrier per K-step.
#define GBM 128
#define GBN 128
#define GBK 64
#define GLD 72

__global__ __launch_bounds__(256) void gemm_nt(
    const bf16* __restrict__ A,
    const void* __restrict__ B1v, const void* __restrict__ B2v, const void* __restrict__ B3v,
    bf16* __restrict__ Cb1, float* __restrict__ Cf1,
    bf16* __restrict__ Cb2, float* __restrict__ Cf2,
    bf16* __restrict__ Cb3, float* __restrict__ Cf3,
    const int* __restrict__ flag, int K,
    int ldb1, int ldb2, int ldb3, int ldc1, int ldc2, int ldc3,
    int ns1, int ns2) {
    __shared__ __align__(16) bf16 As[2][GBM * GLD];
    __shared__ __align__(16) bf16 Bs[2][GBN * GLD];

    // bx-major XCD ordering: XCD x owns bx in [x*nbxp, (x+1)*nbxp), by-fastest.
    // (gridDim.x % 8 == 0 for all launches)
    const int nbxp = (int)gridDim.x >> 3;
    int id = blockIdx.y * gridDim.x + blockIdx.x;
    const int xcd = id & 7;
    const int j = id >> 3;
    const int bx = xcd * nbxp + j / (int)gridDim.y;
    const int by = j % (int)gridDim.y;

    const void* Bv;
    bf16* Cb;
    float* Cf;
    int n0, ldb, ldc;
    if (bx < ns1) {
        Bv = B1v; Cb = Cb1; Cf = Cf1; n0 = bx * GBN; ldb = ldb1; ldc = ldc1;
    } else if (bx < ns1 + ns2) {
        Bv = B2v; Cb = Cb2; Cf = Cf2; n0 = (bx - ns1) * GBN; ldb = ldb2; ldc = ldc2;
    } else {
        Bv = B3v; Cb = Cb3; Cf = Cf3; n0 = (bx - ns1 - ns2) * GBN; ldb = ldb3; ldc = ldc3;
    }
    const int m0 = by * GBM;

    const bool bBf16 = (*flag) != 0;
    const bf16*  Bb = (const bf16*)Bv;
    const float* Bf = (const float*)Bv;

    const int tid  = threadIdx.x;
    const int wave = tid >> 6;
    const int lane = tid & 63;
    const int l15  = lane & 15;
    const int quad = lane >> 4;
    const int wm = (wave >> 1) * 64;
    const int wn = (wave & 1) * 64;

    // per-thread staging coords (constant across tiles)
    const int ar[4] = { (0 * 256 + tid) >> 3, (1 * 256 + tid) >> 3,
                        (2 * 256 + tid) >> 3, (3 * 256 + tid) >> 3 };
    const int ak = tid & 7;

    f32x4 acc[4][4];
#pragma unroll
    for (int i = 0; i < 4; ++i)
#pragma unroll
        for (int j2 = 0; j2 < 4; ++j2) acc[i][j2] = {0.f, 0.f, 0.f, 0.f};

    // single staging reg set (round-9 schedule; bf16 conversion at load)
    bf16x8 aReg[4];
    bf16   bReg[4][8];

#define LOAD_TILE(k0)                                                          \
    {                                                                          \
        _Pragma("unroll")                                                      \
        for (int p = 0; p < 4; ++p)                                            \
            aReg[p] = *(const bf16x8*)&A[(size_t)(m0 + ar[p]) * K + (k0) + ak * 8]; \
        if (bBf16) {                                                           \
            _Pragma("unroll")                                                  \
            for (int p = 0; p < 4; ++p) {                                      \
                const int w16 = wave * 4 + p;                                  \
                const int n = (w16 & 1) * 64 + lane, kc = w16 >> 1;            \
                _Pragma("unroll")                                              \
                for (int e = 0; e < 8; ++e)                                    \
                    bReg[p][e] = Bb[(size_t)((k0) + kc * 8 + e) * ldb + n0 + n]; \
            }                                                                  \
        } else {                                                               \
            _Pragma("unroll")                                                  \
            for (int p = 0; p < 4; ++p) {                                      \
                const int w16 = wave * 4 + p;                                  \
                const int n = (w16 & 1) * 64 + lane, kc = w16 >> 1;            \
                _Pragma("unroll")                                              \
                for (int e = 0; e < 8; ++e)                                    \
                    bReg[p][e] = (bf16)Bf[(size_t)((k0) + kc * 8 + e) * ldb + n0 + n]; \
            }                                                                  \
        }                                                                      \
    }

#define WRITE_TILE(buf)                                                        \
    {                                                                          \
        _Pragma("unroll")                                                      \
        for (int p = 0; p < 4; ++p)                                            \
            *(bf16x8*)&As[buf][ar[p] * GLD + ak * 8] = aReg[p];                \
        _Pragma("unroll")                                                      \
        for (int p = 0; p < 4; ++p) {                                          \
            const int w16 = wave * 4 + p;                                      \
            const int n = (w16 & 1) * 64 + lane, kc = w16 >> 1;                \
            bf16x8 bv;                                                         \
            _Pragma("unroll")                                                  \
            for (int e = 0; e < 8; ++e) bv[e] = bReg[p][e];                    \
            *(bf16x8*)&Bs[buf][n * GLD + kc * 8] = bv;                         \
        }                                                                      \
    }

#define COMPUTE_TILE(buf)                                                      \
    {                                                                          \
        _Pragma("unroll")                                                      \
        for (int kk = 0; kk < GBK; kk += 32) {                                 \
            bf16x8 af[4], bfr[4];                                              \
            _Pragma("unroll")                                                  \
            for (int i = 0; i < 4; ++i)                                        \
                af[i] = *(const bf16x8*)&As[buf][(wm + i * 16 + l15) * GLD + kk + quad * 8]; \
            _Pragma("unroll")                                                  \
            for (int j3 = 0; j3 < 4; ++j3)                                     \
                bfr[j3] = *(const bf16x8*)&Bs[buf][(wn + j3 * 16 + l15) * GLD + kk + quad * 8]; \
            _Pragma("unroll")                                                  \
            for (int i = 0; i < 4; ++i)                                        \
                _Pragma("unroll")                                              \
                for (int j3 = 0; j3 < 4; ++j3)                                 \
                    acc[i][j3] = MFMA16(af[i], bfr[j3], acc[i][j3]);           \
        }                                                                      \
    }

    const int nt = K >> 6;   // GBK = 64
    LOAD_TILE(0);
    WRITE_TILE(0);
    __syncthreads();
    int cur = 0;
    for (int t = 0; t < nt; ++t) {
        if (t + 1 < nt) LOAD_TILE((t + 1) << 6);
        COMPUTE_TILE(cur);
        if (t + 1 < nt) {
            WRITE_TILE(cur ^ 1);
            __syncthreads();
        }
        cur ^= 1;
    }
#undef LOAD_TILE
#undef WRITE_TILE
#undef COMPUTE_TILE

#pragma unroll
    for (int i = 0; i < 4; ++i)
#pragma unroll
        for (int j2 = 0; j2 < 4; ++j2)
#pragma unroll
            for (int r = 0; r < 4; ++r) {
                const int row = m0 + wm + i * 16 + quad * 4 + r;
                const int col = n0 + wn + j2 * 16 + l15;
                const float v = acc[i][j2][r];
                if (Cb) Cb[(size_t)row * ldc + col] = (bf16)v;
                if (Cf) Cf[(size_t)row * ldc + col] = v;
            }
}

// ---------------------------------------------------------------- norm + rope
__global__ __launch_bounds__(256) void norm_rope(const bf16* __restrict__ src,
                                                 bf16* __restrict__ dst_bf,
                                                 float* __restrict__ dst_f32,
                                                 const bf16* __restrict__ w,
                                                 const int* __restrict__ positions,
                                                 int H) {
    const int wid  = blockIdx.x * 4 + (threadIdx.x >> 6);
    const int lane = threadIdx.x & 63;
    const int token = wid / H, head = wid % H;
    const bf16* s = src + ((size_t)token * H + head) * 128;
    const float f0 = (float)s[lane], f1 = (float)s[lane + 64];
    float ss = f0 * f0 + f1 * f1;
    for (int off = 32; off >= 1; off >>= 1) ss += __shfl_xor(ss, off);
    const float inv_rms = rsqrtf(ss * (1.0f / 128.0f) + 1e-6f);
    const float n0 = f0 * inv_rms * (float)w[lane];
    const float n1 = f1 * inv_rms * (float)w[lane + 64];
    const float pos = (float)positions[token];
    const float inv_ts = expf((float)lane * (-13.815510557964274f / 64.0f));
    const float ang = pos * inv_ts;
    const float sn = sinf(ang), cs = cosf(ang);
    const float o0 = n0 * cs - n1 * sn;
    const float o1 = n1 * cs + n0 * sn;
    const size_t base = ((size_t)token * H + head) * 128;
    if (dst_bf)  { dst_bf[base + lane] = (bf16)o0;  dst_bf[base + lane + 64] = (bf16)o1; }
    if (dst_f32) { dst_f32[base + lane] = o0;       dst_f32[base + lane + 64] = o1; }
}

// ---------------------------------------------------------------- MFMA flash attention
// 1024 blocks; work id chunked so each XCD handles 4 consecutive heads
// (one KV head, ~1MB, resident in its private L2). Block = 4 waves; wave w
// owns q rows [qt*64 + w*16, +16) of head h. KV tiles of 32 keys in LDS.
__global__ __launch_bounds__(256) void flash_attn(const bf16* __restrict__ Q,
                                                  const bf16* __restrict__ Kg,
                                                  const bf16* __restrict__ Vg,
                                                  bf16* __restrict__ Og) {
    __shared__ __align__(16) bf16 Ks[32 * 128];     // 8 KiB, swizzled
    __shared__ __align__(16) bf16 Vt[128 * 40];     // 10 KiB, V^T padded
    __shared__ __align__(16) bf16 Ps[4][16 * 40];   // 5 KiB, per-wave P

    int id = blockIdx.y * 32 + blockIdx.x;
    id = (id & 7) * 128 + (id >> 3);        // XCD-chunked
    const int h  = id >> 5;                 // head-major within chunk
    const int qt = 31 - (id & 31);          // heavy (long-loop) tiles first
    const int kvh  = h >> 2;
    const int tid  = threadIdx.x;
    const int wave = tid >> 6;
    const int lane = tid & 63;
    const int l15  = lane & 15;
    const int quad = lane >> 4;
    const int q0   = qt * 64;
    const int qw0  = q0 + wave * 16;
    const int myq  = qw0 + l15;
    const float scale = 0.08838834764831845f;  // 1/sqrt(128)

    bf16x8 qf[4];
    {
        const bf16* qrow = Q + ((size_t)myq * 32 + h) * 128;
#pragma unroll
        for (int kc = 0; kc < 4; ++kc)
            qf[kc] = *(const bf16x8*)&qrow[kc * 32 + quad * 8];
    }

    f32x4 oacc[8];
#pragma unroll
    for (int i = 0; i < 8; ++i) oacc[i] = {0.f, 0.f, 0.f, 0.f};
    float m_run = -1e30f, l_run = 0.f;

    const int ksr  = tid & 31;
    const int kscb = tid >> 5;
    const int vr0  = (tid & 15) * 2;
    const int vcb  = tid >> 4;

    char* kbytes = (char*)Ks;
    char* vbytes = (char*)Vt;
    char* pbytes = (char*)&Ps[wave][0];

    const int ntiles = (q0 + 64) >> 5;
    for (int kt = 0; kt < ntiles; ++kt) {
        const int kb = kt * 32;
        {
            const bf16* src = Kg + ((size_t)(kb + ksr) * 8 + kvh) * 128;
            const bf16x8 v0 = *(const bf16x8*)&src[kscb * 8];
            const bf16x8 v1 = *(const bf16x8*)&src[(kscb + 8) * 8];
            const int b0 = (ksr * 256 + kscb * 16) ^ ((ksr & 7) << 4);
            const int b1 = (ksr * 256 + (kscb + 8) * 16) ^ ((ksr & 7) << 4);
            *(bf16x8*)(kbytes + b0) = v0;
            *(bf16x8*)(kbytes + b1) = v1;
        }
        {
            const bf16* s0 = Vg + ((size_t)(kb + vr0) * 8 + kvh) * 128 + vcb * 8;
            const bf16x8 a = *(const bf16x8*)s0;
            const bf16x8 b = *(const bf16x8*)(s0 + 1024);
#pragma unroll
            for (int e = 0; e < 8; ++e) {
                union { bf16 hh[2]; unsigned int u; } pk;
                pk.hh[0] = a[e]; pk.hh[1] = b[e];
                *(unsigned int*)(vbytes + (vcb * 8 + e) * 80 + vr0 * 2) = pk.u;
            }
        }
        __syncthreads();

        f32x4 sacc[2];
        sacc[0] = {0.f, 0.f, 0.f, 0.f};
        sacc[1] = {0.f, 0.f, 0.f, 0.f};
#pragma unroll
        for (int st = 0; st < 2; ++st) {
            const int row = st * 16 + l15;
#pragma unroll
            for (int kc = 0; kc < 4; ++kc) {
                const int bofs = (row * 256 + kc * 64 + quad * 16) ^ ((row & 7) << 4);
                const bf16x8 kf = *(const bf16x8*)(kbytes + bofs);
                sacc[st] = MFMA16(kf, qf[kc], sacc[st]);
            }
        }

        float sv[8];
        float pm = -1e30f;
#pragma unroll
        for (int st = 0; st < 2; ++st)
#pragma unroll
            for (int r = 0; r < 4; ++r) {
                const int key = kb + st * 16 + quad * 4 + r;
                float s = sacc[st][r] * scale;
                if (key > myq) s = -1e30f;
                sv[st * 4 + r] = s;
                pm = fmaxf(pm, s);
            }
        pm = fmaxf(pm, __shfl_xor(pm, 16));
        pm = fmaxf(pm, __shfl_xor(pm, 32));
        const float m_new = fmaxf(m_run, pm);
        const float corr = __expf(m_run - m_new);
        float ps = 0.f;
        bf16 pb[8];
#pragma unroll
        for (int i = 0; i < 8; ++i) {
            const float p = __expf(sv[i] - m_new);
            ps += p;
            pb[i] = (bf16)p;
        }
        ps += __shfl_xor(ps, 16);
        ps += __shfl_xor(ps, 32);
        l_run = l_run * corr + ps;
        m_run = m_new;

#pragma unroll
        for (int st = 0; st < 2; ++st)
#pragma unroll
            for (int r = 0; r < 4; ++r)
                *(bf16*)(pbytes + l15 * 80 + (st * 16 + quad * 4 + r) * 2) = pb[st * 4 + r];

        float corrq[4];
#pragma unroll
        for (int r = 0; r < 4; ++r) corrq[r] = __shfl(corr, quad * 4 + r);
#pragma unroll
        for (int nt = 0; nt < 8; ++nt)
#pragma unroll
            for (int r = 0; r < 4; ++r) oacc[nt][r] *= corrq[r];

        const bf16x8 pf = *(const bf16x8*)(pbytes + l15 * 80 + quad * 16);
#pragma unroll
        for (int nt = 0; nt < 8; ++nt) {
            const bf16x8 vf = *(const bf16x8*)(vbytes + (nt * 16 + l15) * 80 + quad * 16);
            oacc[nt] = MFMA16(pf, vf, oacc[nt]);
        }
        __syncthreads();
    }

    const float rinv = 1.0f / l_run;
    float linv[4];
#pragma unroll
    for (int r = 0; r < 4; ++r) linv[r] = __shfl(rinv, quad * 4 + r);
#pragma unroll
    for (int nt = 0; nt < 8; ++nt)
#pragma unroll
        for (int r = 0; r < 4; ++r) {
            const int row = qw0 + quad * 4 + r;
            Og[((size_t)row * 32 + h) * 128 + nt * 16 + l15] = (bf16)(oacc[nt][r] * linv[r]);
        }
}

// ---------------------------------------------------------------- launch
extern "C" void kernel_launch(void* const* d_in, const int* in_sizes, int n_in,
                              void* d_out, int out_size, void* d_ws, size_t ws_size,
                              hipStream_t stream) {
    const void* x  = d_in[0];   // [2048][4096]  fp32 or bf16 (auto-detected)
    const void* Wq = d_in[1];   // [4096][4096]
    const void* Wk = d_in[2];   // [4096][1024]
    const void* Wv = d_in[3];   // [4096][1024]
    const void* Wo = d_in[4];   // [4096][4096]
    const void* qw = d_in[5];   // [128]
    const void* kw = d_in[6];   // [128]
    const int* positions = (const int*)d_in[8];

    char* ws = (char*)d_ws;
    int*  flag    = (int*)ws;
    bf16* qwc     = (bf16*)(ws + 64);
    bf16* kwc     = (bf16*)(ws + 64 + 256);
    bf16* kq      = (bf16*)(ws + 4096);                 // [2048][8][128] bf16
    bf16* vb      = (bf16*)(ws + 4096 + 4194304);       // [2048][8][128] bf16
    bf16* xb      = (bf16*)(ws + 4096 + 8388608);       // [2048][4096] bf16 (pre-flash)
    bf16* attnbuf = (bf16*)(ws + 4096 + 8388608);       // [2048][32][128] bf16 (post-flash)

    float* outf = (float*)d_out;           // [2048][4096] fp32
    float* Kof  = outf + 8388608;          // [2048][8][128] fp32
    float* Vof  = outf + 10485760;         // [2048][8][128] fp32
    bf16*  qb   = (bf16*)d_out;            // bf16 q scratch in out's first 16 MiB

    detect_convert<<<1, 256, 0, stream>>>((const unsigned short*)Wq, qw, kw, flag, qwc, kwc);
    convert_x<<<4096, 256, 0, stream>>>(x, xb, flag);

    // All three projections in ONE launch: bx [0,32) Wq -> qb, [32,40) Wk -> kq,
    // [40,48) Wv -> vb + Vof. 768 blocks.
    gemm_nt<<<dim3(48, 16), 256, 0, stream>>>(
        xb, Wq, Wk, Wv,
        qb, nullptr, kq, nullptr, vb, Vof,
        flag, 4096,
        4096, 1024, 1024, 4096, 1024, 1024,
        32, 8);

    // Norm+RoPE. q in-place bf16; k in-place bf16 (attn input) + fp32 (output 1).
    norm_rope<<<16384, 256, 0, stream>>>(qb, qb, nullptr, qwc, positions, 32);
    norm_rope<<<4096, 256, 0, stream>>>(kq, kq, Kof, kwc, positions, 8);

    // Flash attention (MFMA) -> attnbuf bf16 [2048][32][128] (overwrites xb).
    flash_attn<<<dim3(32, 32), 256, 0, stream>>>(qb, kq, vb, attnbuf);

    // Output projection -> fp32 out (overwrites qb scratch after last use).
    gemm_nt<<<dim3(32, 16), 256, 0, stream>>>(
        attnbuf, Wo, Wo, Wo,
        nullptr, outf, nullptr, nullptr, nullptr, nullptr,
        flag, 4096,
        4096, 4096, 4096, 4096, 4096, 4096,
        32, 0);
}

// Round 7
// 639.926 us; speedup vs baseline: 1.3662x; 1.1131x over previous
//
#include <hip/hip_runtime.h>

// Qwen3 attention block, MI355X gfx950.
// Round 12: GLL-A + 3-BLOCKS/CU. Round-11 counters: QKV 285us, MfmaUtil 14.6,
// VALU 21, HBM 9.5, Occ 16.5 -- all idle => latency-bound; FETCH 180MB proved
// traffic was never binding (round-10 theory wrong). Two structural taxes:
// A's reg round-trip (fix: global_load_lds, T21 recipe -- linear LDS dest +
// inverse-swizzled global source + XOR-swizzled fragment reads) and 72KB LDS
// capping occupancy at 2 blocks/CU (fix: single-buffer Bs -- its prefetch
// regs are the 2nd buffer -- As 2x16K + Bs 18K = 50KB -> 3 blocks/CU, grid
// 768 fully resident). 2 barriers/tile now, loads still a full compute-phase
// ahead. B scalar-gather path unchanged (validated). norm_rope: __expf /
// __sincosf. flash_attn untouched (no counters yet -- don't optimize blind).
// ws (24 MiB + 4 KiB): [0,4K) control {flag, qwc[128], kwc[128]}
//   [4K,+4M) kq bf16 | [+4M,+8M) vb bf16 | [+8M,+24M) xb bf16 then attnbuf
// d_out (fp32): out [0,8388608) | k [8388608,10485760) | v [10485760,12582912)
//   (bf16 q scratch borrows out's first 16 MiB; overwritten by final gemm)

typedef __bf16 bf16;
typedef __bf16 bf16x8 __attribute__((ext_vector_type(8)));
typedef float  f32x4  __attribute__((ext_vector_type(4)));

#define MFMA16(a, b, c) __builtin_amdgcn_mfma_f32_16x16x32_bf16((a), (b), (c), 0, 0, 0)

// async global->LDS, 16B per lane; LDS dest = wave-uniform base + lane*16
__device__ __forceinline__ void gll16(const void* g, void* l) {
    __builtin_amdgcn_global_load_lds(
        (const __attribute__((address_space(1))) void*)g,
        (__attribute__((address_space(3))) void*)l,
        16, 0, 0);
}

// ---------------------------------------------------------------- dtype probe
__global__ __launch_bounds__(256) void detect_convert(
    const unsigned short* __restrict__ probe,   // Wq bits
    const void* __restrict__ qw_raw, const void* __restrict__ kw_raw,
    int* __restrict__ flag, bf16* __restrict__ qwc, bf16* __restrict__ kwc) {
    __shared__ int cnt;
    if (threadIdx.x == 0) cnt = 0;
    __syncthreads();
    int local = 0;
    for (int i = 0; i < 4; ++i) {
        const unsigned short w = probe[(threadIdx.x * 4 + i) * 2];
        const int e = (w >> 7) & 0xFF;
        if (e >= 90 && e <= 140) ++local;
    }
    atomicAdd(&cnt, local);
    __syncthreads();
    const bool isbf16 = cnt >= 700;
    if (threadIdx.x == 0) *flag = isbf16 ? 1 : 0;
    const int t = threadIdx.x;
    if (t < 128)
        qwc[t] = isbf16 ? ((const bf16*)qw_raw)[t] : (bf16)((const float*)qw_raw)[t];
    else
        kwc[t - 128] = isbf16 ? ((const bf16*)kw_raw)[t - 128] : (bf16)((const float*)kw_raw)[t - 128];
}

// ---------------------------------------------------------------- x -> bf16
__global__ __launch_bounds__(256) void convert_x(const void* __restrict__ xv,
                                                 bf16* __restrict__ xb,
                                                 const int* __restrict__ flag) {
    const size_t i8 = ((size_t)blockIdx.x * 256 + threadIdx.x) * 8;
    if (*flag) {
        *(bf16x8*)&xb[i8] = *(const bf16x8*)&((const bf16*)xv)[i8];
    } else {
        const f32x4 a = *(const f32x4*)&((const float*)xv)[i8];
        const f32x4 b = *(const f32x4*)&((const float*)xv)[i8 + 4];
        bf16x8 o;
#pragma unroll
        for (int e = 0; e < 4; ++e) { o[e] = (bf16)a[e]; o[e + 4] = (bf16)b[e]; }
        *(bf16x8*)&xb[i8] = o;
    }
}

// ---------------------------------------------------------------- MFMA GEMM
// A bf16 [M][K] row-major, staged via global_load_lds into linear [128][64]
// LDS with XOR swizzle applied on the SOURCE address (T21): LDS slot
// (row, c) holds A[row][c ^ (row&7)]; fragment reads XOR the same way ->
// conflict-free without padding. B (fp32/bf16) [K][N] staged via per-column
// scalar loads to regs (the prefetch regs double as Bs's second buffer),
// single-buffered Bs[128][72]. LDS total 50KB -> 3 blocks/CU.
#define GBM 128
#define GBN 128
#define GBK 64
#define GLD 72

__global__ __launch_bounds__(256) void gemm_nt(
    const bf16* __restrict__ A,
    const void* __restrict__ B1v, const void* __restrict__ B2v, const void* __restrict__ B3v,
    bf16* __restrict__ Cb1, float* __restrict__ Cf1,
    bf16* __restrict__ Cb2, float* __restrict__ Cf2,
    bf16* __restrict__ Cb3, float* __restrict__ Cf3,
    const int* __restrict__ flag, int K,
    int ldb1, int ldb2, int ldb3, int ldc1, int ldc2, int ldc3,
    int ns1, int ns2) {
    __shared__ __align__(16) bf16 As[2][GBM * 64];   // 2 x 16 KiB, gll target
    __shared__ __align__(16) bf16 Bs[GBN * GLD];     // 18 KiB, single buffer

    // bx-major XCD ordering: XCD x owns bx in [x*nbxp, (x+1)*nbxp), by-fastest.
    const int nbxp = (int)gridDim.x >> 3;
    int id = blockIdx.y * gridDim.x + blockIdx.x;
    const int xcd = id & 7;
    const int j = id >> 3;
    const int bx = xcd * nbxp + j / (int)gridDim.y;
    const int by = j % (int)gridDim.y;

    const void* Bv;
    bf16* Cb;
    float* Cf;
    int n0, ldb, ldc;
    if (bx < ns1) {
        Bv = B1v; Cb = Cb1; Cf = Cf1; n0 = bx * GBN; ldb = ldb1; ldc = ldc1;
    } else if (bx < ns1 + ns2) {
        Bv = B2v; Cb = Cb2; Cf = Cf2; n0 = (bx - ns1) * GBN; ldb = ldb2; ldc = ldc2;
    } else {
        Bv = B3v; Cb = Cb3; Cf = Cf3; n0 = (bx - ns1 - ns2) * GBN; ldb = ldb3; ldc = ldc3;
    }
    const int m0 = by * GBM;

    const bool bBf16 = (*flag) != 0;
    const bf16*  Bb = (const bf16*)Bv;
    const float* Bf = (const float*)Bv;

    const int tid  = threadIdx.x;
    const int wave = tid >> 6;
    const int lane = tid & 63;
    const int l15  = lane & 15;
    const int quad = lane >> 4;
    const int axor = l15 & 7;
    const int wm = (wave >> 1) * 64;
    const int wn = (wave & 1) * 64;

    // A gll source: lane l of wave w, chunk p covers LDS rows p*32+w*8+(l>>3),
    // 16B col (l&7); source col inverse-swizzled: (l&7)^(l>>3).
    const int l8 = lane >> 3;
    const bf16* aP = A + (size_t)(m0 + wave * 8 + l8) * K + (((lane & 7) ^ l8) << 3);

    f32x4 acc[4][4];
#pragma unroll
    for (int i = 0; i < 4; ++i)
#pragma unroll
        for (int j2 = 0; j2 < 4; ++j2) acc[i][j2] = {0.f, 0.f, 0.f, 0.f};

    bf16 bReg[4][8];   // B prefetch regs (double as Bs's 2nd buffer)

#define LOAD_B(k0)                                                             \
    {                                                                          \
        if (bBf16) {                                                           \
            _Pragma("unroll")                                                  \
            for (int p = 0; p < 4; ++p) {                                      \
                const int w16 = wave * 4 + p;                                  \
                const int n = (w16 & 1) * 64 + lane, kc = w16 >> 1;            \
                _Pragma("unroll")                                              \
                for (int e = 0; e < 8; ++e)                                    \
                    bReg[p][e] = Bb[(size_t)((k0) + kc * 8 + e) * ldb + n0 + n]; \
            }                                                                  \
        } else {                                                               \
            _Pragma("unroll")                                                  \
            for (int p = 0; p < 4; ++p) {                                      \
                const int w16 = wave * 4 + p;                                  \
                const int n = (w16 & 1) * 64 + lane, kc = w16 >> 1;            \
                _Pragma("unroll")                                              \
                for (int e = 0; e < 8; ++e)                                    \
                    bReg[p][e] = (bf16)Bf[(size_t)((k0) + kc * 8 + e) * ldb + n0 + n]; \
            }                                                                  \
        }                                                                      \
    }

#define GLL_A(k0, buf)                                                         \
    {                                                                          \
        _Pragma("unroll")                                                      \
        for (int p = 0; p < 4; ++p)                                            \
            gll16(aP + (size_t)p * 32 * K + (k0),                              \
                  &As[buf][p * 2048 + wave * 512]);                            \
    }

#define WRITE_B()                                                              \
    {                                                                          \
        _Pragma("unroll")                                                      \
        for (int p = 0; p < 4; ++p) {                                          \
            const int w16 = wave * 4 + p;                                      \
            const int n = (w16 & 1) * 64 + lane, kc = w16 >> 1;                \
            bf16x8 bv;                                                         \
            _Pragma("unroll")                                                  \
            for (int e = 0; e < 8; ++e) bv[e] = bReg[p][e];                    \
            *(bf16x8*)&Bs[n * GLD + kc * 8] = bv;                              \
        }                                                                      \
    }

#define COMPUTE(buf)                                                           \
    {                                                                          \
        _Pragma("unroll")                                                      \
        for (int kk = 0; kk < GBK; kk += 32) {                                 \
            bf16x8 af[4], bfr[4];                                              \
            _Pragma("unroll")                                                  \
            for (int i = 0; i < 4; ++i)                                        \
                af[i] = *(const bf16x8*)&As[buf][(wm + i * 16 + l15) * 64 +    \
                        ((((kk) >> 3) + quad) ^ axor) * 8];                    \
            _Pragma("unroll")                                                  \
            for (int j3 = 0; j3 < 4; ++j3)                                     \
                bfr[j3] = *(const bf16x8*)&Bs[(wn + j3 * 16 + l15) * GLD + kk + quad * 8]; \
            _Pragma("unroll")                                                  \
            for (int i = 0; i < 4; ++i)                                        \
                _Pragma("unroll")                                              \
                for (int j3 = 0; j3 < 4; ++j3)                                 \
                    acc[i][j3] = MFMA16(af[i], bfr[j3], acc[i][j3]);           \
        }                                                                      \
    }

    const int nt = K >> 6;   // GBK = 64
    // prologue: tile 0 -> Bs + As[0]
    LOAD_B(0);
    GLL_A(0, 0);
    WRITE_B();            // waits B regs (gll may still be in flight)
    __syncthreads();      // drains vmcnt(0): As[0] + Bs ready
    int cur = 0;
    for (int t = 0; t < nt; ++t) {
        if (t + 1 < nt) {
            LOAD_B((t + 1) << 6);       // -> regs (async)
            GLL_A((t + 1) << 6, cur ^ 1);  // -> other A buffer (async)
        }
        COMPUTE(cur);
        __syncthreads();                // all waves done reading Bs
        if (t + 1 < nt) {
            WRITE_B();                  // regs -> Bs
            __syncthreads();            // Bs + As[cur^1] ready (vmcnt drained)
        }
        cur ^= 1;
    }
#undef LOAD_B
#undef GLL_A
#undef WRITE_B
#undef COMPUTE

#pragma unroll
    for (int i = 0; i < 4; ++i)
#pragma unroll
        for (int j2 = 0; j2 < 4; ++j2)
#pragma unroll
            for (int r = 0; r < 4; ++r) {
                const int row = m0 + wm + i * 16 + quad * 4 + r;
                const int col = n0 + wn + j2 * 16 + l15;
                const float v = acc[i][j2][r];
                if (Cb) Cb[(size_t)row * ldc + col] = (bf16)v;
                if (Cf) Cf[(size_t)row * ldc + col] = v;
            }
}

// ---------------------------------------------------------------- norm + rope
__global__ __launch_bounds__(256) void norm_rope(const bf16* __restrict__ src,
                                                 bf16* __restrict__ dst_bf,
                                                 float* __restrict__ dst_f32,
                                                 const bf16* __restrict__ w,
                                                 const int* __restrict__ positions,
                                                 int H) {
    const int wid  = blockIdx.x * 4 + (threadIdx.x >> 6);
    const int lane = threadIdx.x & 63;
    const int token = wid / H, head = wid % H;
    const bf16* s = src + ((size_t)token * H + head) * 128;
    const float f0 = (float)s[lane], f1 = (float)s[lane + 64];
    float ss = f0 * f0 + f1 * f1;
    for (int off = 32; off >= 1; off >>= 1) ss += __shfl_xor(ss, off);
    const float inv_rms = rsqrtf(ss * (1.0f / 128.0f) + 1e-6f);
    const float n0 = f0 * inv_rms * (float)w[lane];
    const float n1 = f1 * inv_rms * (float)w[lane + 64];
    const float pos = (float)positions[token];
    const float inv_ts = __expf((float)lane * (-13.815510557964274f / 64.0f));
    const float ang = pos * inv_ts;
    float sn, cs;
    __sincosf(ang, &sn, &cs);
    const float o0 = n0 * cs - n1 * sn;
    const float o1 = n1 * cs + n0 * sn;
    const size_t base = ((size_t)token * H + head) * 128;
    if (dst_bf)  { dst_bf[base + lane] = (bf16)o0;  dst_bf[base + lane + 64] = (bf16)o1; }
    if (dst_f32) { dst_f32[base + lane] = o0;       dst_f32[base + lane + 64] = o1; }
}

// ---------------------------------------------------------------- MFMA flash attention
// 1024 blocks; work id chunked so each XCD handles 4 consecutive heads
// (one KV head, ~1MB, resident in its private L2). Block = 4 waves; wave w
// owns q rows [qt*64 + w*16, +16) of head h. KV tiles of 32 keys in LDS.
__global__ __launch_bounds__(256) void flash_attn(const bf16* __restrict__ Q,
                                                  const bf16* __restrict__ Kg,
                                                  const bf16* __restrict__ Vg,
                                                  bf16* __restrict__ Og) {
    __shared__ __align__(16) bf16 Ks[32 * 128];     // 8 KiB, swizzled
    __shared__ __align__(16) bf16 Vt[128 * 40];     // 10 KiB, V^T padded
    __shared__ __align__(16) bf16 Ps[4][16 * 40];   // 5 KiB, per-wave P

    int id = blockIdx.y * 32 + blockIdx.x;
    id = (id & 7) * 128 + (id >> 3);        // XCD-chunked
    const int h  = id >> 5;                 // head-major within chunk
    const int qt = 31 - (id & 31);          // heavy (long-loop) tiles first
    const int kvh  = h >> 2;
    const int tid  = threadIdx.x;
    const int wave = tid >> 6;
    const int lane = tid & 63;
    const int l15  = lane & 15;
    const int quad = lane >> 4;
    const int q0   = qt * 64;
    const int qw0  = q0 + wave * 16;
    const int myq  = qw0 + l15;
    const float scale = 0.08838834764831845f;  // 1/sqrt(128)

    bf16x8 qf[4];
    {
        const bf16* qrow = Q + ((size_t)myq * 32 + h) * 128;
#pragma unroll
        for (int kc = 0; kc < 4; ++kc)
            qf[kc] = *(const bf16x8*)&qrow[kc * 32 + quad * 8];
    }

    f32x4 oacc[8];
#pragma unroll
    for (int i = 0; i < 8; ++i) oacc[i] = {0.f, 0.f, 0.f, 0.f};
    float m_run = -1e30f, l_run = 0.f;

    const int ksr  = tid & 31;
    const int kscb = tid >> 5;
    const int vr0  = (tid & 15) * 2;
    const int vcb  = tid >> 4;

    char* kbytes = (char*)Ks;
    char* vbytes = (char*)Vt;
    char* pbytes = (char*)&Ps[wave][0];

    const int ntiles = (q0 + 64) >> 5;
    for (int kt = 0; kt < ntiles; ++kt) {
        const int kb = kt * 32;
        {
            const bf16* src = Kg + ((size_t)(kb + ksr) * 8 + kvh) * 128;
            const bf16x8 v0 = *(const bf16x8*)&src[kscb * 8];
            const bf16x8 v1 = *(const bf16x8*)&src[(kscb + 8) * 8];
            const int b0 = (ksr * 256 + kscb * 16) ^ ((ksr & 7) << 4);
            const int b1 = (ksr * 256 + (kscb + 8) * 16) ^ ((ksr & 7) << 4);
            *(bf16x8*)(kbytes + b0) = v0;
            *(bf16x8*)(kbytes + b1) = v1;
        }
        {
            const bf16* s0 = Vg + ((size_t)(kb + vr0) * 8 + kvh) * 128 + vcb * 8;
            const bf16x8 a = *(const bf16x8*)s0;
            const bf16x8 b = *(const bf16x8*)(s0 + 1024);
#pragma unroll
            for (int e = 0; e < 8; ++e) {
                union { bf16 hh[2]; unsigned int u; } pk;
                pk.hh[0] = a[e]; pk.hh[1] = b[e];
                *(unsigned int*)(vbytes + (vcb * 8 + e) * 80 + vr0 * 2) = pk.u;
            }
        }
        __syncthreads();

        f32x4 sacc[2];
        sacc[0] = {0.f, 0.f, 0.f, 0.f};
        sacc[1] = {0.f, 0.f, 0.f, 0.f};
#pragma unroll
        for (int st = 0; st < 2; ++st) {
            const int row = st * 16 + l15;
#pragma unroll
            for (int kc = 0; kc < 4; ++kc) {
                const int bofs = (row * 256 + kc * 64 + quad * 16) ^ ((row & 7) << 4);
                const bf16x8 kf = *(const bf16x8*)(kbytes + bofs);
                sacc[st] = MFMA16(kf, qf[kc], sacc[st]);
            }
        }

        float sv[8];
        float pm = -1e30f;
#pragma unroll
        for (int st = 0; st < 2; ++st)
#pragma unroll
            for (int r = 0; r < 4; ++r) {
                const int key = kb + st * 16 + quad * 4 + r;
                float s = sacc[st][r] * scale;
                if (key > myq) s = -1e30f;
                sv[st * 4 + r] = s;
                pm = fmaxf(pm, s);
            }
        pm = fmaxf(pm, __shfl_xor(pm, 16));
        pm = fmaxf(pm, __shfl_xor(pm, 32));
        const float m_new = fmaxf(m_run, pm);
        const float corr = __expf(m_run - m_new);
        float ps = 0.f;
        bf16 pb[8];
#pragma unroll
        for (int i = 0; i < 8; ++i) {
            const float p = __expf(sv[i] - m_new);
            ps += p;
            pb[i] = (bf16)p;
        }
        ps += __shfl_xor(ps, 16);
        ps += __shfl_xor(ps, 32);
        l_run = l_run * corr + ps;
        m_run = m_new;

#pragma unroll
        for (int st = 0; st < 2; ++st)
#pragma unroll
            for (int r = 0; r < 4; ++r)
                *(bf16*)(pbytes + l15 * 80 + (st * 16 + quad * 4 + r) * 2) = pb[st * 4 + r];

        float corrq[4];
#pragma unroll
        for (int r = 0; r < 4; ++r) corrq[r] = __shfl(corr, quad * 4 + r);
#pragma unroll
        for (int nt = 0; nt < 8; ++nt)
#pragma unroll
            for (int r = 0; r < 4; ++r) oacc[nt][r] *= corrq[r];

        const bf16x8 pf = *(const bf16x8*)(pbytes + l15 * 80 + quad * 16);
#pragma unroll
        for (int nt = 0; nt < 8; ++nt) {
            const bf16x8 vf = *(const bf16x8*)(vbytes + (nt * 16 + l15) * 80 + quad * 16);
            oacc[nt] = MFMA16(pf, vf, oacc[nt]);
        }
        __syncthreads();
    }

    const float rinv = 1.0f / l_run;
    float linv[4];
#pragma unroll
    for (int r = 0; r < 4; ++r) linv[r] = __shfl(rinv, quad * 4 + r);
#pragma unroll
    for (int nt = 0; nt < 8; ++nt)
#pragma unroll
        for (int r = 0; r < 4; ++r) {
            const int row = qw0 + quad * 4 + r;
            Og[((size_t)row * 32 + h) * 128 + nt * 16 + l15] = (bf16)(oacc[nt][r] * linv[r]);
        }
}

// ---------------------------------------------------------------- launch
extern "C" void kernel_launch(void* const* d_in, const int* in_sizes, int n_in,
                              void* d_out, int out_size, void* d_ws, size_t ws_size,
                              hipStream_t stream) {
    const void* x  = d_in[0];   // [2048][4096]  fp32 or bf16 (auto-detected)
    const void* Wq = d_in[1];   // [4096][4096]
    const void* Wk = d_in[2];   // [4096][1024]
    const void* Wv = d_in[3];   // [4096][1024]
    const void* Wo = d_in[4];   // [4096][4096]
    const void* qw = d_in[5];   // [128]
    const void* kw = d_in[6];   // [128]
    const int* positions = (const int*)d_in[8];

    char* ws = (char*)d_ws;
    int*  flag    = (int*)ws;
    bf16* qwc     = (bf16*)(ws + 64);
    bf16* kwc     = (bf16*)(ws + 64 + 256);
    bf16* kq      = (bf16*)(ws + 4096);                 // [2048][8][128] bf16
    bf16* vb      = (bf16*)(ws + 4096 + 4194304);       // [2048][8][128] bf16
    bf16* xb      = (bf16*)(ws + 4096 + 8388608);       // [2048][4096] bf16 (pre-flash)
    bf16* attnbuf = (bf16*)(ws + 4096 + 8388608);       // [2048][32][128] bf16 (post-flash)

    float* outf = (float*)d_out;           // [2048][4096] fp32
    float* Kof  = outf + 8388608;          // [2048][8][128] fp32
    float* Vof  = outf + 10485760;         // [2048][8][128] fp32
    bf16*  qb   = (bf16*)d_out;            // bf16 q scratch in out's first 16 MiB

    detect_convert<<<1, 256, 0, stream>>>((const unsigned short*)Wq, qw, kw, flag, qwc, kwc);
    convert_x<<<4096, 256, 0, stream>>>(x, xb, flag);

    // All three projections in ONE launch: bx [0,32) Wq -> qb, [32,40) Wk -> kq,
    // [40,48) Wv -> vb + Vof. 768 blocks = exactly 3/CU resident.
    gemm_nt<<<dim3(48, 16), 256, 0, stream>>>(
        xb, Wq, Wk, Wv,
        qb, nullptr, kq, nullptr, vb, Vof,
        flag, 4096,
        4096, 1024, 1024, 4096, 1024, 1024,
        32, 8);

    // Norm+RoPE. q in-place bf16; k in-place bf16 (attn input) + fp32 (output 1).
    norm_rope<<<16384, 256, 0, stream>>>(qb, qb, nullptr, qwc, positions, 32);
    norm_rope<<<4096, 256, 0, stream>>>(kq, kq, Kof, kwc, positions, 8);

    // Flash attention (MFMA) -> attnbuf bf16 [2048][32][128] (overwrites xb).
    flash_attn<<<dim3(32, 32), 256, 0, stream>>>(qb, kq, vb, attnbuf);

    // Output projection -> fp32 out (overwrites qb scratch after last use).
    gemm_nt<<<dim3(32, 16), 256, 0, stream>>>(
        attnbuf, Wo, Wo, Wo,
        nullptr, outf, nullptr, nullptr, nullptr, nullptr,
        flag, 4096,
        4096, 4096, 4096, 4096, 4096, 4096,
        32, 0);
}